// Round 8
// baseline (210.791 us; speedup 1.0000x reference)
//
#include <hip/hip_runtime.h>
#include <hip/hip_bf16.h>

#define N_PTS 100000
#define KNN   16
#define NK    (N_PTS * KNN)
#define CIN   64
#define CMID  64
#define COUT  128

#define HSLC    64           // histogram slices
#define SEG_CNT 25000        // counters per segment (4 segments cover 100k)
#define SEG_U32 12500

// ---------------- ws layout (bytes) ----------------
// [0, 25,600,000)           z2h: [2][N][64] fp16 (channel-halved rows, 128 B each);
//                           head first holds pc (64 x 100k ushort partials, 12.8MB)
// [25,600,000, +12,800,000) z1h (N*64 fp16, row-major)
// [38,400,000, +400,000)    counts (float)
// [38,800,000, +1,536)      stats: S1[64] Q1[64] S2[128] Q2[128]  (memset 0)
// [38,801,536, +16,384)     W2f: A-frag-swizzled, sign(g2)-folded W2 (fp16)
// [38,817,920, +8,192)      W1f: A-frag-swizzled W1 (fp16)
#define OFF_Z2H   0
#define OFF_Z1H   25600000
#define OFF_CNT   38400000
#define OFF_STATS 38800000
#define OFF_W2F   38801536
#define OFF_W1F   38817920

typedef __attribute__((ext_vector_type(8))) _Float16 f16x8;
typedef __attribute__((ext_vector_type(2))) __fp16 fp16x2;
typedef __attribute__((ext_vector_type(4))) float f32x4;
union F8 { uint4 u; f16x8 v; };
union PK { fp16x2 v; unsigned u; };
union UH { unsigned u; _Float16 h[2]; };

__device__ __forceinline__ unsigned pk2(float a, float b) {
    PK p; p.v = __builtin_amdgcn_cvt_pkrtz(a, b); return p.u;
}
__device__ __forceinline__ unsigned pkmax(unsigned a, unsigned b) {
    unsigned d; asm("v_pk_max_f16 %0, %1, %2" : "=v"(d) : "v"(a), "v"(b)); return d;
}

// ---- 1. segmented LDS histogram: 4 segments x 64 slices = 256 blocks ----
__global__ __launch_bounds__(256) void hist_k(const int* __restrict__ idx,
                                              unsigned short* __restrict__ pc) {
    __shared__ unsigned int smem[SEG_U32];     // 50 KB
    int seg  = blockIdx.x & 3;
    int slc  = blockIdx.x >> 2;                // 0..63
    int base = seg * SEG_CNT;

    for (int i = threadIdx.x; i < SEG_U32; i += 256) smem[i] = 0;
    __syncthreads();

    const int4* ip = (const int4*)idx;
    const int per = NK / 4 / HSLC;             // 6250 int4 per slice
    int s = slc * per, e = s + per;
    for (int i = s + threadIdx.x; i < e; i += 256) {
        int4 v = ip[i];
        int a;
        a = v.x - base; if ((unsigned)a < (unsigned)SEG_CNT)
            atomicAdd(&smem[a >> 1], 1u << ((a & 1) * 16));
        a = v.y - base; if ((unsigned)a < (unsigned)SEG_CNT)
            atomicAdd(&smem[a >> 1], 1u << ((a & 1) * 16));
        a = v.z - base; if ((unsigned)a < (unsigned)SEG_CNT)
            atomicAdd(&smem[a >> 1], 1u << ((a & 1) * 16));
        a = v.w - base; if ((unsigned)a < (unsigned)SEG_CNT)
            atomicAdd(&smem[a >> 1], 1u << ((a & 1) * 16));
    }
    __syncthreads();

    unsigned int* outp = (unsigned int*)(pc + (size_t)slc * N_PTS) + seg * SEG_U32;
    for (int i = threadIdx.x; i < SEG_U32; i += 256) outp[i] = smem[i];
}

// ---- 2. counts = sum of 64 partials; blocks 196/197 swizzle W2/W1 (A-frag, fp16) ----
__global__ __launch_bounds__(256) void sum_counts_k(const unsigned short* __restrict__ pc,
                                                    float* __restrict__ counts,
                                                    const float* __restrict__ W2,
                                                    const float* __restrict__ g2,
                                                    _Float16* __restrict__ w2f,
                                                    const float* __restrict__ W1,
                                                    _Float16* __restrict__ w1f) {
    if (blockIdx.x == 196) {
        // A-frag: e = ((cht*2+kh)*64 + lane)*8 + j ; A[m=ch][k], m=lane&15, k=quad*8+j
        for (int e = threadIdx.x; e < 8192; e += 256) {
            int j = e & 7, lane = (e >> 3) & 63, kh = (e >> 9) & 1, cht = e >> 10;
            int k = kh * 32 + (lane >> 4) * 8 + j;
            int n = cht * 16 + (lane & 15);
            w2f[e] = (_Float16)(__builtin_copysignf(1.f, g2[n]) * W2[k * COUT + n]);
        }
        return;
    }
    if (blockIdx.x == 197) {
        for (int e = threadIdx.x; e < 4096; e += 256) {
            int j = e & 7, lane = (e >> 3) & 63, kh = (e >> 9) & 1, cht = e >> 10;
            int k = kh * 32 + (lane >> 4) * 8 + j;
            int n = cht * 16 + (lane & 15);
            w1f[e] = (_Float16)(W1[k * CMID + n]);
        }
        return;
    }
    int i = blockIdx.x * 256 + threadIdx.x;    // uint-pair index over N_PTS/2
    if (i >= N_PTS / 2) return;
    const unsigned int* p = (const unsigned int*)pc;
    unsigned int u = 0;
    #pragma unroll
    for (int s = 0; s < HSLC; s++) u += p[s * (N_PTS / 2) + i];
    float2 r;
    r.x = (float)(u & 0xffffu);
    r.y = (float)(u >> 16);
    ((float2*)counts)[i] = r;
}

// ---- 3. MFMA gemm1 (W as A, feat as B -> D[ch][pt]): z1h = f16(feat@W1+b1), stats fused ----
__global__ __launch_bounds__(256) void gemm1_k(const float* __restrict__ feat,
                                               const _Float16* __restrict__ w1f,
                                               const float* __restrict__ b1,
                                               const float* __restrict__ counts,
                                               _Float16* __restrict__ z1h,
                                               float* __restrict__ S1,
                                               float* __restrict__ Q1) {
    int lane = threadIdx.x & 63, wid = threadIdx.x >> 6;
    int il = lane & 15, quad = lane >> 4;

    f16x8 wf[4][2];
    const uint4* wp = (const uint4*)w1f;
    #pragma unroll
    for (int cht = 0; cht < 4; cht++) {
        F8 t0; t0.u = wp[(cht * 2 + 0) * 64 + lane]; wf[cht][0] = t0.v;
        F8 t1; t1.u = wp[(cht * 2 + 1) * 64 + lane]; wf[cht][1] = t1.v;
    }
    float4 bias[4];
    #pragma unroll
    for (int cht = 0; cht < 4; cht++) bias[cht] = *(const float4*)(b1 + cht * 16 + quad * 4);

    float s[4][4], q[4][4];
    #pragma unroll
    for (int c = 0; c < 4; c++)
        #pragma unroll
        for (int r = 0; r < 4; r++) { s[c][r] = 0.f; q[c][r] = 0.f; }

    int wgid = blockIdx.x * 4 + wid;
    for (int tile = wgid; tile < N_PTS / 16; tile += gridDim.x * 4) {
        int m0 = tile * 16;
        const float* fr = feat + (size_t)(m0 + il) * 64;
        float4 fa = *(const float4*)(fr + quad * 8);
        float4 fb = *(const float4*)(fr + quad * 8 + 4);
        float4 fc = *(const float4*)(fr + 32 + quad * 8);
        float4 fd = *(const float4*)(fr + 32 + quad * 8 + 4);
        F8 F0, F1;
        F0.u.x = pk2(fa.x, fa.y); F0.u.y = pk2(fa.z, fa.w);
        F0.u.z = pk2(fb.x, fb.y); F0.u.w = pk2(fb.z, fb.w);
        F1.u.x = pk2(fc.x, fc.y); F1.u.y = pk2(fc.z, fc.w);
        F1.u.z = pk2(fd.x, fd.y); F1.u.w = pk2(fd.z, fd.w);
        float cnt = counts[m0 + il];
        #pragma unroll
        for (int cht = 0; cht < 4; cht++) {
            f32x4 acc = {bias[cht].x, bias[cht].y, bias[cht].z, bias[cht].w};
            acc = __builtin_amdgcn_mfma_f32_16x16x32_f16(wf[cht][0], F0.v, acc, 0, 0, 0);
            acc = __builtin_amdgcn_mfma_f32_16x16x32_f16(wf[cht][1], F1.v, acc, 0, 0, 0);
            // lane holds channels cht*16+quad*4+{0..3} of point m0+il
            uint2 pv;
            pv.x = pk2(acc[0], acc[1]);
            pv.y = pk2(acc[2], acc[3]);
            *(uint2*)(z1h + (size_t)(m0 + il) * 64 + cht * 16 + quad * 4) = pv;
            #pragma unroll
            for (int r = 0; r < 4; r++) {
                s[cht][r] = fmaf(cnt, acc[r], s[cht][r]);
                q[cht][r] = fmaf(cnt * acc[r], acc[r], q[cht][r]);
            }
        }
    }
    #pragma unroll
    for (int m = 1; m <= 8; m <<= 1) {
        #pragma unroll
        for (int c = 0; c < 4; c++)
            #pragma unroll
            for (int r = 0; r < 4; r++) {
                s[c][r] += __shfl_xor(s[c][r], m, 64);
                q[c][r] += __shfl_xor(q[c][r], m, 64);
            }
    }
    __shared__ float sred[2][4][64];
    if (il == 0) {
        #pragma unroll
        for (int c = 0; c < 4; c++)
            #pragma unroll
            for (int r = 0; r < 4; r++) {
                sred[0][wid][c * 16 + quad * 4 + r] = s[c][r];
                sred[1][wid][c * 16 + quad * 4 + r] = q[c][r];
            }
    }
    __syncthreads();
    if (threadIdx.x < 128) {
        int which = threadIdx.x >> 6, c = threadIdx.x & 63;
        float t = sred[which][0][c] + sred[which][1][c] + sred[which][2][c] + sred[which][3][c];
        atomicAdd(which ? &Q1[c] : &S1[c], t);
    }
}

// ---- 4. MFMA gemm2 (W2' as A): z2h = f16( sign(g2)*(relu(z1*A1+B1)@W2+b2) ), stats fused ----
__device__ __forceinline__ f16x8 bnrelu16(uint4 r, float4 alo, float4 ahi,
                                          float4 blo, float4 bhi) {
    UH u0, u1, u2, u3;
    u0.u = r.x; u1.u = r.y; u2.u = r.z; u3.u = r.w;
    float z0 = (float)u0.h[0], z1 = (float)u0.h[1];
    float z2 = (float)u1.h[0], z3 = (float)u1.h[1];
    float z4 = (float)u2.h[0], z5 = (float)u2.h[1];
    float z6 = (float)u3.h[0], z7 = (float)u3.h[1];
    F8 o;
    o.u.x = pk2(fmaxf(fmaf(alo.x, z0, blo.x), 0.f), fmaxf(fmaf(alo.y, z1, blo.y), 0.f));
    o.u.y = pk2(fmaxf(fmaf(alo.z, z2, blo.z), 0.f), fmaxf(fmaf(alo.w, z3, blo.w), 0.f));
    o.u.z = pk2(fmaxf(fmaf(ahi.x, z4, bhi.x), 0.f), fmaxf(fmaf(ahi.y, z5, bhi.y), 0.f));
    o.u.w = pk2(fmaxf(fmaf(ahi.z, z6, bhi.z), 0.f), fmaxf(fmaf(ahi.w, z7, bhi.w), 0.f));
    return o.v;
}

__global__ __launch_bounds__(256) void gemm2_k(const _Float16* __restrict__ z1h,
                                               const _Float16* __restrict__ w2f,
                                               const float* __restrict__ S1,
                                               const float* __restrict__ Q1,
                                               const float* __restrict__ g1,
                                               const float* __restrict__ be1,
                                               const float* __restrict__ b2,
                                               const float* __restrict__ g2,
                                               const float* __restrict__ counts,
                                               _Float16* __restrict__ z2h,
                                               float* __restrict__ S2,
                                               float* __restrict__ Q2) {
    __shared__ float Al[64], Bl[64], Bl2[128];
    if (threadIdx.x < 64) {
        const float inv = 1.0f / (float)NK;
        float m = S1[threadIdx.x] * inv;
        float v = Q1[threadIdx.x] * inv - m * m;
        float a = g1[threadIdx.x] * rsqrtf(v + 1e-5f);
        Al[threadIdx.x] = a;
        Bl[threadIdx.x] = be1[threadIdx.x] - m * a;
    }
    if (threadIdx.x < 128)
        Bl2[threadIdx.x] = __builtin_copysignf(1.f, g2[threadIdx.x]) * b2[threadIdx.x];
    __syncthreads();

    int lane = threadIdx.x & 63, wid = threadIdx.x >> 6;
    int il = lane & 15, quad = lane >> 4;

    float4 a0lo = *(const float4*)(Al + quad * 8);
    float4 a0hi = *(const float4*)(Al + quad * 8 + 4);
    float4 b0lo = *(const float4*)(Bl + quad * 8);
    float4 b0hi = *(const float4*)(Bl + quad * 8 + 4);
    float4 a1lo = *(const float4*)(Al + 32 + quad * 8);
    float4 a1hi = *(const float4*)(Al + 32 + quad * 8 + 4);
    float4 b1lo = *(const float4*)(Bl + 32 + quad * 8);
    float4 b1hi = *(const float4*)(Bl + 32 + quad * 8 + 4);

    f16x8 wf[8][2];
    const uint4* wp = (const uint4*)w2f;
    #pragma unroll
    for (int cht = 0; cht < 8; cht++) {
        F8 t0; t0.u = wp[(cht * 2 + 0) * 64 + lane]; wf[cht][0] = t0.v;
        F8 t1; t1.u = wp[(cht * 2 + 1) * 64 + lane]; wf[cht][1] = t1.v;
    }

    float s[8][4], q[8][4];
    #pragma unroll
    for (int c = 0; c < 8; c++)
        #pragma unroll
        for (int r = 0; r < 4; r++) { s[c][r] = 0.f; q[c][r] = 0.f; }

    int wgid = blockIdx.x * 4 + wid;
    for (int tile = wgid; tile < N_PTS / 16; tile += gridDim.x * 4) {
        int m0 = tile * 16;
        const uint4* ar = (const uint4*)(z1h + (size_t)(m0 + il) * 64);
        uint4 ra0 = ar[quad];
        uint4 ra1 = ar[4 + quad];
        f16x8 af0 = bnrelu16(ra0, a0lo, a0hi, b0lo, b0hi);
        f16x8 af1 = bnrelu16(ra1, a1lo, a1hi, b1lo, b1hi);
        float cnt = counts[m0 + il];
        #pragma unroll
        for (int cht = 0; cht < 8; cht++) {
            float4 bb = *(const float4*)(Bl2 + cht * 16 + quad * 4);
            f32x4 acc = {bb.x, bb.y, bb.z, bb.w};
            acc = __builtin_amdgcn_mfma_f32_16x16x32_f16(wf[cht][0], af0, acc, 0, 0, 0);
            acc = __builtin_amdgcn_mfma_f32_16x16x32_f16(wf[cht][1], af1, acc, 0, 0, 0);
            // lane holds channels cht*16+quad*4+{0..3} of point m0+il
            uint2 pv;
            pv.x = pk2(acc[0], acc[1]);
            pv.y = pk2(acc[2], acc[3]);
            size_t base = ((size_t)(cht >> 2) * N_PTS + m0 + il) * 64 + (cht & 3) * 16 + quad * 4;
            *(uint2*)(z2h + base) = pv;
            #pragma unroll
            for (int r = 0; r < 4; r++) {
                s[cht][r] = fmaf(cnt, acc[r], s[cht][r]);
                q[cht][r] = fmaf(cnt * acc[r], acc[r], q[cht][r]);
            }
        }
    }
    #pragma unroll
    for (int m = 1; m <= 8; m <<= 1) {
        #pragma unroll
        for (int c = 0; c < 8; c++)
            #pragma unroll
            for (int r = 0; r < 4; r++) {
                s[c][r] += __shfl_xor(s[c][r], m, 64);
                q[c][r] += __shfl_xor(q[c][r], m, 64);
            }
    }
    __shared__ float sred[2][4][128];
    if (il == 0) {
        #pragma unroll
        for (int c = 0; c < 8; c++)
            #pragma unroll
            for (int r = 0; r < 4; r++) {
                sred[0][wid][c * 16 + quad * 4 + r] = s[c][r];
                sred[1][wid][c * 16 + quad * 4 + r] = q[c][r];
            }
    }
    __syncthreads();
    {
        int which = threadIdx.x >> 7, c = threadIdx.x & 127;
        float t = sred[which][0][c] + sred[which][1][c] + sred[which][2][c] + sred[which][3][c];
        atomicAdd(which ? &Q2[c] : &S2[c], t);
    }
}

// ---- 5. gather: out[n,c] = relu(a'_c * max_k z2'[idx,c] + b'_c), a' = |g2|/sigma >= 0 ----
__global__ __launch_bounds__(256) void gather_k(const unsigned int* __restrict__ z2u,
                                                const int* __restrict__ idx,
                                                const float* __restrict__ S2,
                                                const float* __restrict__ Q2,
                                                const float* __restrict__ g2,
                                                const float* __restrict__ be2,
                                                float* __restrict__ out) {
    int lane = threadIdx.x & 63, wid = threadIdx.x >> 6;
    int half = blockIdx.x / (N_PTS / 8);
    int n    = (blockIdx.x % (N_PTS / 8)) * 8 + wid * 2 + (lane >> 5);
    int sl   = lane & 31;

    const float inv = 1.0f / (float)NK;
    int ci = half * 32 + sl;
    float2 Sv = ((const float2*)S2)[ci];
    float2 Qv = ((const float2*)Q2)[ci];
    float2 gv = ((const float2*)g2)[ci];
    float2 bv = ((const float2*)be2)[ci];
    float m0c = Sv.x * inv, m1c = Sv.y * inv;
    float a0 = fabsf(gv.x) * rsqrtf(Qv.x * inv - m0c * m0c + 1e-5f);
    float a1 = fabsf(gv.y) * rsqrtf(Qv.y * inv - m1c * m1c + 1e-5f);
    float b0 = bv.x - m0c * a0;
    float b1 = bv.y - m1c * a1;

    const int* ip = idx + n * KNN;
    const unsigned int* zh = z2u + (size_t)half * N_PTS * 32;
    unsigned mx = 0xFC00FC00u;                 // (-inf, -inf) fp16
    #pragma unroll
    for (int k = 0; k < KNN; k++) {
        int j = ip[k];
        mx = pkmax(mx, zh[(size_t)j * 32 + sl]);
    }
    UH u; u.u = mx;
    float f0 = (float)u.h[0], f1 = (float)u.h[1];
    float2 r;
    r.x = fmaxf(fmaf(a0, f0, b0), 0.f);
    r.y = fmaxf(fmaf(a1, f1, b1), 0.f);
    ((float2*)(out + (size_t)n * COUT + half * 64))[sl] = r;
}

extern "C" void kernel_launch(void* const* d_in, const int* in_sizes, int n_in,
                              void* d_out, int out_size, void* d_ws, size_t ws_size,
                              hipStream_t stream) {
    const float* feat = (const float*)d_in[0];
    const int*   idx  = (const int*)d_in[1];
    const float* W1   = (const float*)d_in[2];
    const float* b1   = (const float*)d_in[3];
    const float* g1   = (const float*)d_in[4];
    const float* be1  = (const float*)d_in[5];
    const float* W2   = (const float*)d_in[6];
    const float* b2   = (const float*)d_in[7];
    const float* g2   = (const float*)d_in[8];
    const float* be2  = (const float*)d_in[9];
    float* out = (float*)d_out;

    char* ws = (char*)d_ws;
    _Float16* z2h = (_Float16*)(ws + OFF_Z2H);
    unsigned short* pc = (unsigned short*)(ws + OFF_Z2H);  // alias, dead before gemm2
    _Float16* z1h = (_Float16*)(ws + OFF_Z1H);
    float* counts = (float*)(ws + OFF_CNT);
    float* S1 = (float*)(ws + OFF_STATS);
    float* Q1 = S1 + 64;
    float* S2 = S1 + 128;
    float* Q2 = S1 + 256;
    _Float16* w2f = (_Float16*)(ws + OFF_W2F);
    _Float16* w1f = (_Float16*)(ws + OFF_W1F);

    (void)hipMemsetAsync(ws + OFF_STATS, 0, 1536, stream);

    hist_k<<<4 * HSLC, 256, 0, stream>>>(idx, pc);
    sum_counts_k<<<198, 256, 0, stream>>>(pc, counts, W2, g2, w2f, W1, w1f);
    gemm1_k<<<512, 256, 0, stream>>>(feat, w1f, b1, counts, z1h, S1, Q1);
    gemm2_k<<<512, 256, 0, stream>>>(z1h, w2f, S1, Q1, g1, be1, b2, g2, counts, z2h, S2, Q2);
    gather_k<<<2 * (N_PTS / 8), 256, 0, stream>>>((const unsigned int*)z2h, idx,
                                                  S2, Q2, g2, be2, out);
}